// Round 1
// baseline (368.468 us; speedup 1.0000x reference)
//
#include <hip/hip_runtime.h>
#include <hip/hip_bf16.h>

// GCN: 3 layers of  relu(A @ (X @ W) + b)  (no relu on layer 3)
// B=32, N=1024, F_IN=F_HID=F_OUT=512, fp32 in/out, bf16 MFMA internally.
//
// Pipeline per layer:
//   GEMM1: supportT = (X @ W)^T      (A=x row-major [N][K], B^T = W^T [F][K], out transposed bf16)
//   GEMM2: x_next  = A @ support + b (A=adj bf16 [N][N], B^T = supportT [F][N], bias+relu epilogue)
// Layer 3 GEMM2 writes fp32 to d_out.

typedef __attribute__((ext_vector_type(8))) short bf16x8s;   // 8 bf16 in 4 VGPRs
typedef __attribute__((ext_vector_type(4))) float f32x4;
typedef __attribute__((ext_vector_type(4))) unsigned short us4;

__device__ __forceinline__ unsigned short f2bf(float f) {
    unsigned u = __builtin_bit_cast(unsigned, f);
    u += 0x7fffu + ((u >> 16) & 1u);          // round-to-nearest-even
    return (unsigned short)(u >> 16);
}

__device__ __forceinline__ void async16(const unsigned short* g, unsigned short* l) {
    __builtin_amdgcn_global_load_lds(
        (const __attribute__((address_space(1))) unsigned int*)g,
        (__attribute__((address_space(3))) unsigned int*)l,
        16, 0, 0);
}

// ---------------- fp32 -> bf16 elementwise convert (vectorized x4) ----------------
__global__ void cvt_f32_bf16(const float* __restrict__ in, unsigned short* __restrict__ out, long n4) {
    long i = (long)blockIdx.x * blockDim.x + threadIdx.x;
    long stride = (long)gridDim.x * blockDim.x;
    for (; i < n4; i += stride) {
        float4 v = ((const float4*)in)[i];
        us4 o;
        o.x = f2bf(v.x); o.y = f2bf(v.y); o.z = f2bf(v.z); o.w = f2bf(v.w);
        ((us4*)out)[i] = o;
    }
}

// ---------------- W[R][C] f32 -> WT[C][R] bf16 (coalesced write) ----------------
__global__ void transpose_cvt(const float* __restrict__ W, unsigned short* __restrict__ WT,
                              int R, int C) {
    int idx = blockIdx.x * 256 + threadIdx.x;   // index over output, contiguous in R
    if (idx >= R * C) return;
    int r = idx % R;
    int c = idx / R;
    WT[(size_t)c * R + r] = f2bf(W[(size_t)r * C + c]);
}

// ---------------- batched GEMM:  C = A @ B  with B given transposed ----------------
// A  : bf16 [bat][M][K]   (ldA = K)
// BT : bf16 [bat][N][K]   (ldBT = K; strideBT==0 -> shared weights)
// TRANS_OUT: write C^T bf16 [bat][N][M];  else row-major [bat][M][N] (+bias, relu, f32 option)
template<bool TRANS_OUT, bool RELU, bool OUT_F32>
__global__ __launch_bounds__(256, 2)
void gemm_bt(const unsigned short* __restrict__ A,
             const unsigned short* __restrict__ BT,
             void* __restrict__ Cout,
             const float* __restrict__ bias,
             int M, int N, int K,
             long sA, long sBT, long sC)
{
    __shared__ unsigned short Alds[128 * 64];
    __shared__ unsigned short Blds[128 * 64];

    const int t    = threadIdx.x;
    const int lane = t & 63;
    const int wid  = t >> 6;
    const int wm   = (wid >> 1) * 64;      // 2x2 wave grid -> 64x64 per wave
    const int wn   = (wid & 1) * 64;
    const int fr   = lane & 15;            // fragment row (A) / col (B)
    const int fk   = (lane >> 4) * 8;      // k sub-offset
    const int r4   = (lane >> 4) * 4;      // C/D row base

    const int tilesN = N >> 7;
    const int bpb    = (M >> 7) * tilesN;
    const int bat    = blockIdx.x / bpb;
    const int tt     = blockIdx.x % bpb;
    const int m0     = (tt / tilesN) << 7;
    const int n0     = (tt % tilesN) << 7;

    const unsigned short* Ab = A  + (size_t)bat * sA;
    const unsigned short* Bb = BT + (size_t)bat * sBT;

    f32x4 acc[4][4];
#pragma unroll
    for (int m = 0; m < 4; ++m)
#pragma unroll
        for (int n = 0; n < 4; ++n) acc[m][n] = f32x4{0.f, 0.f, 0.f, 0.f};

    // staging map: thread t covers 16B chunk (t&7) of tile-row (t>>3), 4 rounds of 32 rows
    const int rowA = m0 + (t >> 3);
    const int rowB = n0 + (t >> 3);
    const int cba  = (t & 7) * 8;          // element offset of chunk within 64-wide k-slice

    for (int k0 = 0; k0 < K; k0 += 64) {
        __syncthreads();                   // previous tile's reads done
        const unsigned short* ga = Ab + (size_t)rowA * K + k0 + cba;
        const unsigned short* gb = Bb + (size_t)rowB * K + k0 + cba;
        unsigned short* la = Alds + t * 8;
        unsigned short* lb = Blds + t * 8;
#pragma unroll
        for (int r = 0; r < 4; ++r) {
            async16(ga + (size_t)r * 32 * K, la + r * 2048);
            async16(gb + (size_t)r * 32 * K, lb + r * 2048);
        }
        __syncthreads();                   // drains vmcnt -> tiles visible
#pragma unroll
        for (int kk = 0; kk < 64; kk += 32) {
            bf16x8s a[4], b[4];
#pragma unroll
            for (int m = 0; m < 4; ++m)
                a[m] = *(const bf16x8s*)&Alds[(wm + m * 16 + fr) * 64 + kk + fk];
#pragma unroll
            for (int n = 0; n < 4; ++n)
                b[n] = *(const bf16x8s*)&Blds[(wn + n * 16 + fr) * 64 + kk + fk];
#pragma unroll
            for (int m = 0; m < 4; ++m)
#pragma unroll
                for (int n = 0; n < 4; ++n)
                    acc[m][n] = __builtin_amdgcn_mfma_f32_16x16x32_bf16(a[m], b[n], acc[m][n], 0, 0, 0);
        }
    }

    if (TRANS_OUT) {
        unsigned short* Ct = (unsigned short*)Cout + (size_t)bat * sC;
#pragma unroll
        for (int n = 0; n < 4; ++n) {
            const int col = n0 + wn + n * 16 + fr;
#pragma unroll
            for (int m = 0; m < 4; ++m) {
                const int row0 = m0 + wm + m * 16 + r4;
                us4 v;
                v.x = f2bf(acc[m][n][0]);
                v.y = f2bf(acc[m][n][1]);
                v.z = f2bf(acc[m][n][2]);
                v.w = f2bf(acc[m][n][3]);
                *(us4*)&Ct[(size_t)col * M + row0] = v;
            }
        }
    } else {
#pragma unroll
        for (int n = 0; n < 4; ++n) {
            const int col = n0 + wn + n * 16 + fr;
            const float bn = bias ? bias[col] : 0.f;
#pragma unroll
            for (int m = 0; m < 4; ++m) {
#pragma unroll
                for (int i = 0; i < 4; ++i) {
                    float v = acc[m][n][i] + bn;
                    if (RELU) v = fmaxf(v, 0.f);
                    const int row = m0 + wm + m * 16 + r4 + i;
                    if (OUT_F32)
                        ((float*)Cout)[(size_t)bat * sC + (size_t)row * N + col] = v;
                    else
                        ((unsigned short*)Cout)[(size_t)bat * sC + (size_t)row * N + col] = f2bf(v);
                }
            }
        }
    }
}

extern "C" void kernel_launch(void* const* d_in, const int* in_sizes, int n_in,
                              void* d_out, int out_size, void* d_ws, size_t ws_size,
                              hipStream_t stream) {
    constexpr int B = 32, N = 1024, F = 512;

    const float* x0f = (const float*)d_in[0];   // [B][N][F]
    const float* adjf = (const float*)d_in[1];  // [B][N][N]
    const float* W1 = (const float*)d_in[2];
    const float* b1 = (const float*)d_in[3];
    const float* W2 = (const float*)d_in[4];
    const float* b2 = (const float*)d_in[5];
    const float* W3 = (const float*)d_in[6];
    const float* b3 = (const float*)d_in[7];

    unsigned short* ws   = (unsigned short*)d_ws;
    unsigned short* adjb = ws;                                   // B*N*N   = 33,554,432 el
    unsigned short* P0   = adjb + (size_t)B * N * N;             // B*N*F   = 16,777,216 el
    unsigned short* P1   = P0 + (size_t)B * N * F;
    unsigned short* P2   = P1 + (size_t)B * N * F;
    unsigned short* WT1  = P2 + (size_t)B * N * F;               // F*F each
    unsigned short* WT2  = WT1 + (size_t)F * F;
    unsigned short* WT3  = WT2 + (size_t)F * F;

    // conversions
    cvt_f32_bf16<<<2048, 256, 0, stream>>>(adjf, adjb, (long)B * N * N / 4);
    cvt_f32_bf16<<<2048, 256, 0, stream>>>(x0f, P0, (long)B * N * F / 4);
    transpose_cvt<<<(F * F) / 256, 256, 0, stream>>>(W1, WT1, F, F);
    transpose_cvt<<<(F * F) / 256, 256, 0, stream>>>(W2, WT2, F, F);
    transpose_cvt<<<(F * F) / 256, 256, 0, stream>>>(W3, WT3, F, F);

    const int gridG = B * (N / 128) * (F / 128);   // 1024 blocks
    const long sX  = (long)N * F;   // x / support strides per batch
    const long sAd = (long)N * N;

    // layer 1
    gemm_bt<true, false, false><<<gridG, 256, 0, stream>>>(P0, WT1, P1, nullptr, N, F, F, sX, 0, sX);
    gemm_bt<false, true, false><<<gridG, 256, 0, stream>>>(adjb, P1, P2, b1, N, F, N, sAd, sX, sX);
    // layer 2
    gemm_bt<true, false, false><<<gridG, 256, 0, stream>>>(P2, WT2, P0, nullptr, N, F, F, sX, 0, sX);
    gemm_bt<false, true, false><<<gridG, 256, 0, stream>>>(adjb, P0, P1, b2, N, F, N, sAd, sX, sX);
    // layer 3 (fp32 out, no relu)
    gemm_bt<true, false, false><<<gridG, 256, 0, stream>>>(P1, WT3, P2, nullptr, N, F, F, sX, 0, sX);
    gemm_bt<false, false, true><<<gridG, 256, 0, stream>>>(adjb, P2, (float*)d_out, b3, N, F, N, sAd, sX, sX);
}

// Round 2
// 299.471 us; speedup vs baseline: 1.2304x; 1.2304x over previous
//
#include <hip/hip_runtime.h>
#include <hip/hip_bf16.h>

// GCN: 3 x [ relu(A @ (X @ W) + b) ]  (no relu layer 3), fp32 I/O, bf16 MFMA.
// GEMM1: supportT = (X@W)^T  ; GEMM2: A @ support + b (bias/relu fused).
// 256x256 tile, BK=64, 512 threads (8 waves, 2Mx4N), double-buffered LDS,
// 4-phase/K-tile counted-vmcnt pipeline (T3+T4), XOR-swizzled LDS (T2),
// setprio around MFMA (T5), chunked XCD block swizzle (T1).

typedef __attribute__((ext_vector_type(8))) short bf16x8s;
typedef __attribute__((ext_vector_type(4))) float f32x4;
typedef __attribute__((ext_vector_type(4))) unsigned short us4;

__device__ __forceinline__ unsigned short f2bf(float f) {
    unsigned u = __builtin_bit_cast(unsigned, f);
    u += 0x7fffu + ((u >> 16) & 1u);          // RNE
    return (unsigned short)(u >> 16);
}

__device__ __forceinline__ void async16(const unsigned short* g, unsigned short* l) {
    __builtin_amdgcn_global_load_lds(
        (const __attribute__((address_space(1))) unsigned int*)g,
        (__attribute__((address_space(3))) unsigned int*)l, 16, 0, 0);
}

#define MFMA_(d, va, vb) d = __builtin_amdgcn_mfma_f32_16x16x32_bf16(va, vb, d, 0, 0, 0)

// ---------------- fp32 -> bf16 convert (x4 vectorized) ----------------
__global__ void cvt_f32_bf16(const float* __restrict__ in, unsigned short* __restrict__ out, long n4) {
    long i = (long)blockIdx.x * blockDim.x + threadIdx.x;
    long stride = (long)gridDim.x * blockDim.x;
    for (; i < n4; i += stride) {
        float4 v = ((const float4*)in)[i];
        us4 o;
        o.x = f2bf(v.x); o.y = f2bf(v.y); o.z = f2bf(v.z); o.w = f2bf(v.w);
        ((us4*)out)[i] = o;
    }
}

// ---------------- W[R][C] f32 -> WT[C][R] bf16 ----------------
__global__ void transpose_cvt(const float* __restrict__ W, unsigned short* __restrict__ WT,
                              int R, int C) {
    int idx = blockIdx.x * 256 + threadIdx.x;
    if (idx >= R * C) return;
    int r = idx % R;
    int c = idx / R;
    WT[(size_t)c * R + r] = f2bf(W[(size_t)r * C + c]);
}

// ---------------- batched GEMM C = A @ B,  B given transposed ----------------
// A  : bf16 [bat][M][K]; BT : bf16 [bat][N][K] (sBT==0 -> shared weights)
// TRANS_OUT: C^T bf16 [bat][N][M]; else row-major [bat][M][N] (+bias/relu/f32)
template<bool TRANS_OUT, bool RELU, bool OUT_F32>
__global__ __launch_bounds__(512, 2)
void gemm256(const unsigned short* __restrict__ A,
             const unsigned short* __restrict__ BT,
             void* __restrict__ Cout,
             const float* __restrict__ bias,
             int M, int N, int K,
             long sA, long sBT, long sC)
{
    __shared__ unsigned short Al[2][256 * 64];   // 32 KiB each buf
    __shared__ unsigned short Bl[2][256 * 64];   // total 128 KiB

    const int t    = threadIdx.x;
    const int lane = t & 63;
    const int wv   = t >> 6;
    const int wm   = wv >> 2;          // 0..1  -> 128-row half
    const int wn   = wv & 3;           // 0..3  -> 64-col strip
    const int fr   = lane & 15;
    const int fk   = (lane >> 4) * 8;  // k-element sub-offset
    const int r4   = (lane >> 4) * 4;

    const int tilesN = N >> 8;
    const int bpb    = (M >> 8) * tilesN;
    // chunked XCD swizzle (grid==256, divisible by 8 -> bijective)
    const int cpx = gridDim.x >> 3;
    const int lb  = (blockIdx.x & 7) * cpx + (blockIdx.x >> 3);
    const int bat = lb / bpb;
    const int tt  = lb % bpb;
    const int m0  = (tt / tilesN) << 8;
    const int n0  = (tt % tilesN) << 8;

    const unsigned short* Ab = A  + (size_t)bat * sA  + (size_t)m0 * K;
    const unsigned short* Bb = BT + (size_t)bat * sBT + (size_t)n0 * K;

    // staging map: chunk c = r*512+t covers LDS elems [c*8, c*8+8) of a half-tile
    // (linear dest for global_load_lds); global source col pre-XOR-swizzled.
    int srow[2], scol[2], lo[2];
#pragma unroll
    for (int r = 0; r < 2; ++r) {
        int c  = r * 512 + t;
        srow[r] = c >> 3;
        scol[r] = ((c & 7) * 8) ^ ((srow[r] & 7) << 3);
        lo[r]   = c * 8;
    }

    auto stageA = [&](int kt, int h) {
        const int buf = kt & 1;
#pragma unroll
        for (int r = 0; r < 2; ++r)
            async16(Ab + (size_t)(h * 128 + srow[r]) * K + kt * 64 + scol[r],
                    &Al[buf][h * 8192 + lo[r]]);
    };
    auto stageB = [&](int kt, int h) {
        const int buf = kt & 1;
#pragma unroll
        for (int r = 0; r < 2; ++r)
            async16(Bb + (size_t)(h * 128 + srow[r]) * K + kt * 64 + scol[r],
                    &Bl[buf][h * 8192 + lo[r]]);
    };
    // swizzled LDS fragment reads (b128)
    auto rdA = [&](int buf, int mf, int kkj) -> bf16x8s {
        int row = wm * 128 + mf * 16 + fr;
        int e   = (kkj * 32 + fk) ^ ((row & 7) << 3);
        return *(const bf16x8s*)&Al[buf][row * 64 + e];
    };
    auto rdB = [&](int buf, int nf, int kkj) -> bf16x8s {
        int row = wn * 64 + nf * 16 + fr;
        int e   = (kkj * 32 + fk) ^ ((row & 7) << 3);
        return *(const bf16x8s*)&Bl[buf][row * 64 + e];
    };

    const int nt = K >> 6;

    f32x4 acc[8][4];
#pragma unroll
    for (int i = 0; i < 8; ++i)
#pragma unroll
        for (int j = 0; j < 4; ++j) acc[i][j] = f32x4{0.f, 0.f, 0.f, 0.f};

    // ---- prologue: tile0 fully + tile1 B-halves; keep tile1-B in flight ----
    stageA(0, 0); stageA(0, 1); stageB(0, 0); stageB(0, 1);
    if (nt > 1) {
        stageB(1, 0); stageB(1, 1);
        asm volatile("s_waitcnt vmcnt(4)" ::: "memory");
    } else {
        asm volatile("s_waitcnt vmcnt(0)" ::: "memory");
    }
    __builtin_amdgcn_s_barrier();

    bf16x8s bfr[4][2];
    for (int it = 0; it < nt; ++it) {
        const int cur = it & 1;
        bf16x8s a0, a1, a2, a3;

        // ---------- phase 0: read all B + A(m0,m1); stage A-half0 of t+1 ----------
#pragma unroll
        for (int nf = 0; nf < 4; ++nf) {
            bfr[nf][0] = rdB(cur, nf, 0);
            bfr[nf][1] = rdB(cur, nf, 1);
        }
        a0 = rdA(cur, 0, 0); a1 = rdA(cur, 0, 1);
        a2 = rdA(cur, 1, 0); a3 = rdA(cur, 1, 1);
        if (it + 1 < nt) stageA(it + 1, 0);
        __builtin_amdgcn_s_barrier();
        asm volatile("s_waitcnt lgkmcnt(0)" ::: "memory");
        __builtin_amdgcn_sched_barrier(0);
        __builtin_amdgcn_s_setprio(1);
#pragma unroll
        for (int nf = 0; nf < 4; ++nf) {
            MFMA_(acc[0][nf], a0, bfr[nf][0]);
            MFMA_(acc[0][nf], a1, bfr[nf][1]);
            MFMA_(acc[1][nf], a2, bfr[nf][0]);
            MFMA_(acc[1][nf], a3, bfr[nf][1]);
        }
        __builtin_amdgcn_s_setprio(0);
        __builtin_amdgcn_s_barrier();

        // ---------- phase 1: A(m2,m3); stage A-half1 of t+1 ----------
        a0 = rdA(cur, 2, 0); a1 = rdA(cur, 2, 1);
        a2 = rdA(cur, 3, 0); a3 = rdA(cur, 3, 1);
        if (it + 1 < nt) stageA(it + 1, 1);
        __builtin_amdgcn_s_barrier();
        asm volatile("s_waitcnt lgkmcnt(0)" ::: "memory");
        __builtin_amdgcn_sched_barrier(0);
        __builtin_amdgcn_s_setprio(1);
#pragma unroll
        for (int nf = 0; nf < 4; ++nf) {
            MFMA_(acc[2][nf], a0, bfr[nf][0]);
            MFMA_(acc[2][nf], a1, bfr[nf][1]);
            MFMA_(acc[3][nf], a2, bfr[nf][0]);
            MFMA_(acc[3][nf], a3, bfr[nf][1]);
        }
        __builtin_amdgcn_s_setprio(0);
        __builtin_amdgcn_s_barrier();

        // ---------- phase 2: A(m4,m5); stage B-half0 of t+2 (B region of cur is dead) ----------
        a0 = rdA(cur, 4, 0); a1 = rdA(cur, 4, 1);
        a2 = rdA(cur, 5, 0); a3 = rdA(cur, 5, 1);
        if (it + 2 < nt) stageB(it + 2, 0);
        __builtin_amdgcn_s_barrier();
        asm volatile("s_waitcnt lgkmcnt(0)" ::: "memory");
        __builtin_amdgcn_sched_barrier(0);
        __builtin_amdgcn_s_setprio(1);
#pragma unroll
        for (int nf = 0; nf < 4; ++nf) {
            MFMA_(acc[4][nf], a0, bfr[nf][0]);
            MFMA_(acc[4][nf], a1, bfr[nf][1]);
            MFMA_(acc[5][nf], a2, bfr[nf][0]);
            MFMA_(acc[5][nf], a3, bfr[nf][1]);
        }
        __builtin_amdgcn_s_setprio(0);
        __builtin_amdgcn_s_barrier();

        // ---------- phase 3: A(m6,m7); stage B-half1 of t+2; end-of-tile wait ----------
        a0 = rdA(cur, 6, 0); a1 = rdA(cur, 6, 1);
        a2 = rdA(cur, 7, 0); a3 = rdA(cur, 7, 1);
        if (it + 2 < nt) stageB(it + 2, 1);
        __builtin_amdgcn_s_barrier();
        asm volatile("s_waitcnt lgkmcnt(0)" ::: "memory");
        __builtin_amdgcn_sched_barrier(0);
        __builtin_amdgcn_s_setprio(1);
#pragma unroll
        for (int nf = 0; nf < 4; ++nf) {
            MFMA_(acc[6][nf], a0, bfr[nf][0]);
            MFMA_(acc[6][nf], a1, bfr[nf][1]);
            MFMA_(acc[7][nf], a2, bfr[nf][0]);
            MFMA_(acc[7][nf], a3, bfr[nf][1]);
        }
        __builtin_amdgcn_s_setprio(0);
        // counted wait: next iter needs tile it+1 fully landed; newest 4 loads
        // (B-halves of tile it+2) may stay in flight.
        if (it < nt - 2)       asm volatile("s_waitcnt vmcnt(4)" ::: "memory");
        else if (it == nt - 2) asm volatile("s_waitcnt vmcnt(0)" ::: "memory");
        __builtin_amdgcn_s_barrier();
    }

    // ---------------- epilogue ----------------
    if (TRANS_OUT) {
        unsigned short* Ct = (unsigned short*)Cout + (size_t)bat * sC;
#pragma unroll
        for (int j = 0; j < 4; ++j) {
            const int col = n0 + wn * 64 + j * 16 + fr;
#pragma unroll
            for (int i = 0; i < 8; ++i) {
                const int row0 = m0 + wm * 128 + i * 16 + r4;
                us4 v;
                v.x = f2bf(acc[i][j][0]); v.y = f2bf(acc[i][j][1]);
                v.z = f2bf(acc[i][j][2]); v.w = f2bf(acc[i][j][3]);
                *(us4*)&Ct[(size_t)col * M + row0] = v;
            }
        }
    } else {
#pragma unroll
        for (int j = 0; j < 4; ++j) {
            const int col = n0 + wn * 64 + j * 16 + fr;
            const float bn = bias ? bias[col] : 0.f;
#pragma unroll
            for (int i = 0; i < 8; ++i) {
#pragma unroll
                for (int e = 0; e < 4; ++e) {
                    float v = acc[i][j][e] + bn;
                    if (RELU) v = fmaxf(v, 0.f);
                    const int row = m0 + wm * 128 + i * 16 + r4 + e;
                    if (OUT_F32)
                        ((float*)Cout)[(size_t)bat * sC + (size_t)row * N + col] = v;
                    else
                        ((unsigned short*)Cout)[(size_t)bat * sC + (size_t)row * N + col] = f2bf(v);
                }
            }
        }
    }
}

extern "C" void kernel_launch(void* const* d_in, const int* in_sizes, int n_in,
                              void* d_out, int out_size, void* d_ws, size_t ws_size,
                              hipStream_t stream) {
    constexpr int B = 32, N = 1024, F = 512;

    const float* x0f  = (const float*)d_in[0];
    const float* adjf = (const float*)d_in[1];
    const float* W1 = (const float*)d_in[2];
    const float* b1 = (const float*)d_in[3];
    const float* W2 = (const float*)d_in[4];
    const float* b2 = (const float*)d_in[5];
    const float* W3 = (const float*)d_in[6];
    const float* b3 = (const float*)d_in[7];

    unsigned short* ws   = (unsigned short*)d_ws;
    unsigned short* adjb = ws;
    unsigned short* P0   = adjb + (size_t)B * N * N;
    unsigned short* P1   = P0 + (size_t)B * N * F;
    unsigned short* P2   = P1 + (size_t)B * N * F;
    unsigned short* WT1  = P2 + (size_t)B * N * F;
    unsigned short* WT2  = WT1 + (size_t)F * F;
    unsigned short* WT3  = WT2 + (size_t)F * F;

    cvt_f32_bf16<<<2048, 256, 0, stream>>>(adjf, adjb, (long)B * N * N / 4);
    cvt_f32_bf16<<<2048, 256, 0, stream>>>(x0f, P0, (long)B * N * F / 4);
    transpose_cvt<<<(F * F) / 256, 256, 0, stream>>>(W1, WT1, F, F);
    transpose_cvt<<<(F * F) / 256, 256, 0, stream>>>(W2, WT2, F, F);
    transpose_cvt<<<(F * F) / 256, 256, 0, stream>>>(W3, WT3, F, F);

    const int grid = B * (N / 256) * (F / 256);   // 256 blocks
    const long sX  = (long)N * F;
    const long sAd = (long)N * N;

    // layer 1
    gemm256<true,  false, false><<<grid, 512, 0, stream>>>(P0,   WT1, P1, nullptr, N, F, F, sX, 0, sX);
    gemm256<false, true,  false><<<grid, 512, 0, stream>>>(adjb, P1,  P2, b1,      N, F, N, sAd, sX, sX);
    // layer 2
    gemm256<true,  false, false><<<grid, 512, 0, stream>>>(P2,   WT2, P0, nullptr, N, F, F, sX, 0, sX);
    gemm256<false, true,  false><<<grid, 512, 0, stream>>>(adjb, P0,  P1, b2,      N, F, N, sAd, sX, sX);
    // layer 3 (fp32 out, no relu)
    gemm256<true,  false, false><<<grid, 512, 0, stream>>>(P1,   WT3, P2, nullptr, N, F, F, sX, 0, sX);
    gemm256<false, false, true ><<<grid, 512, 0, stream>>>(adjb, P2,  (float*)d_out, b3, N, F, N, sAd, sX, sX);
}

// Round 3
// 269.935 us; speedup vs baseline: 1.3650x; 1.1094x over previous
//
#include <hip/hip_runtime.h>
#include <hip/hip_bf16.h>

// GCN: 3 x [ relu(A @ (X @ W) + b) ]  (no relu layer 3), fp32 I/O, bf16 MFMA.
// All-row-major chain:
//   G1: T  = W^T @ X^T = (X@W)^T : gemm(A=WT [F][F], BT=X [N][F]) -> T [F][N]
//   G2: X' = adj @ T^T (+b, relu): gemm(A=adj [N][N], BT=T [F][N]) -> X' [N][F]
// Every operand/output is row-major; no transposed epilogue anywhere.
// 256x256 tile, BK=64, 512 thr (8 waves 2Mx4N), dbuf LDS, 4-phase counted-vmcnt
// pipeline (T3+T4), XOR-swizzled LDS (T2), setprio (T5), XCD swizzle (T1),
// LDS-bounced us8 coalesced epilogue stores.

typedef __attribute__((ext_vector_type(8))) short bf16x8s;
typedef __attribute__((ext_vector_type(4))) float f32x4;
typedef __attribute__((ext_vector_type(4))) unsigned short us4;
typedef __attribute__((ext_vector_type(8))) unsigned short us8;

__device__ __forceinline__ unsigned short f2bf(float f) {
    unsigned u = __builtin_bit_cast(unsigned, f);
    u += 0x7fffu + ((u >> 16) & 1u);          // RNE
    return (unsigned short)(u >> 16);
}

__device__ __forceinline__ void async16(const unsigned short* g, unsigned short* l) {
    __builtin_amdgcn_global_load_lds(
        (const __attribute__((address_space(1))) unsigned int*)g,
        (__attribute__((address_space(3))) unsigned int*)l, 16, 0, 0);
}

#define MFMA_(d, va, vb) d = __builtin_amdgcn_mfma_f32_16x16x32_bf16(va, vb, d, 0, 0, 0)

// ---------------- fp32 -> bf16 convert (x4 vectorized) ----------------
__global__ void cvt_f32_bf16(const float* __restrict__ in, unsigned short* __restrict__ out, long n4) {
    long i = (long)blockIdx.x * blockDim.x + threadIdx.x;
    long stride = (long)gridDim.x * blockDim.x;
    for (; i < n4; i += stride) {
        float4 v = ((const float4*)in)[i];
        us4 o;
        o.x = f2bf(v.x); o.y = f2bf(v.y); o.z = f2bf(v.z); o.w = f2bf(v.w);
        ((us4*)out)[i] = o;
    }
}

// ---------------- W[R][C] f32 -> WT[C][R] bf16 ----------------
__global__ void transpose_cvt(const float* __restrict__ W, unsigned short* __restrict__ WT,
                              int R, int C) {
    int idx = blockIdx.x * 256 + threadIdx.x;
    if (idx >= R * C) return;
    int r = idx % R;
    int c = idx / R;
    WT[(size_t)c * R + r] = f2bf(W[(size_t)r * C + c]);
}

// ---------------- batched GEMM C = A @ B,  B given transposed ----------------
// A : bf16 [bat][M][K] (sA==0 -> shared); BT : bf16 [bat][N][K] (sBT==0 -> shared)
// Out row-major [bat][M][N]; bias indexed by col (nullptr ok); optional relu/f32.
template<bool RELU, bool OUT_F32>
__global__ __launch_bounds__(512, 2)
void gemm256(const unsigned short* __restrict__ A,
             const unsigned short* __restrict__ BT,
             void* __restrict__ Cout,
             const float* __restrict__ bias,
             int M, int N, int K,
             long sA, long sBT, long sC)
{
    __shared__ unsigned short Lraw[65536];     // 128 KiB: A dbuf 64K | B dbuf 64K

    const int t    = threadIdx.x;
    const int lane = t & 63;
    const int wv   = t >> 6;
    const int wm   = wv >> 2;          // 0..1  -> 128-row half
    const int wn   = wv & 3;           // 0..3  -> 64-col strip
    const int fr   = lane & 15;
    const int fk   = (lane >> 4) * 8;
    const int r4   = (lane >> 4) * 4;

    const int tilesN = N >> 8;
    const int bpb    = (M >> 8) * tilesN;
    // chunked XCD swizzle (grid==256, divisible by 8 -> bijective)
    const int cpx = gridDim.x >> 3;
    const int lb  = (blockIdx.x & 7) * cpx + (blockIdx.x >> 3);
    const int bat = lb / bpb;
    const int tt  = lb % bpb;
    const int m0  = (tt / tilesN) << 8;
    const int n0  = (tt % tilesN) << 8;

    const unsigned short* Ab = A  + (size_t)bat * sA  + (size_t)m0 * K;
    const unsigned short* Bb = BT + (size_t)bat * sBT + (size_t)n0 * K;

    // staging map: chunk c = r*512+t covers LDS elems [c*8, c*8+8) of a half-tile
    // (linear dest for global_load_lds); global source col pre-XOR-swizzled.
    int srow[2], scol[2], lo[2];
#pragma unroll
    for (int r = 0; r < 2; ++r) {
        int c   = r * 512 + t;
        srow[r] = c >> 3;
        scol[r] = ((c & 7) * 8) ^ ((srow[r] & 7) << 3);
        lo[r]   = c * 8;
    }

    auto stageA = [&](int kt, int h) {
        unsigned short* base = Lraw + (kt & 1) * 16384;
#pragma unroll
        for (int r = 0; r < 2; ++r)
            async16(Ab + (size_t)(h * 128 + srow[r]) * K + kt * 64 + scol[r],
                    base + h * 8192 + lo[r]);
    };
    auto stageB = [&](int kt, int h) {
        unsigned short* base = Lraw + 32768 + (kt & 1) * 16384;
#pragma unroll
        for (int r = 0; r < 2; ++r)
            async16(Bb + (size_t)(h * 128 + srow[r]) * K + kt * 64 + scol[r],
                    base + h * 8192 + lo[r]);
    };
    auto rdA = [&](int buf, int mf, int kkj) -> bf16x8s {
        int row = wm * 128 + mf * 16 + fr;
        int e   = (kkj * 32 + fk) ^ ((row & 7) << 3);
        return *(const bf16x8s*)&Lraw[buf * 16384 + row * 64 + e];
    };
    auto rdB = [&](int buf, int nf, int kkj) -> bf16x8s {
        int row = wn * 64 + nf * 16 + fr;
        int e   = (kkj * 32 + fk) ^ ((row & 7) << 3);
        return *(const bf16x8s*)&Lraw[32768 + buf * 16384 + row * 64 + e];
    };

    const int nt = K >> 6;

    f32x4 acc[8][4];
#pragma unroll
    for (int i = 0; i < 8; ++i)
#pragma unroll
        for (int j = 0; j < 4; ++j) acc[i][j] = f32x4{0.f, 0.f, 0.f, 0.f};

    // ---- prologue: tile0 fully + tile1 B-halves; keep tile1-B in flight ----
    stageA(0, 0); stageA(0, 1); stageB(0, 0); stageB(0, 1);
    if (nt > 1) {
        stageB(1, 0); stageB(1, 1);
        asm volatile("s_waitcnt vmcnt(4)" ::: "memory");
    } else {
        asm volatile("s_waitcnt vmcnt(0)" ::: "memory");
    }
    __builtin_amdgcn_s_barrier();

    bf16x8s bfr[4][2];
    for (int it = 0; it < nt; ++it) {
        const int cur = it & 1;
        bf16x8s a0, a1, a2, a3;

        // phase 0: read all B + A(m0,m1); stage A-half0 of t+1
#pragma unroll
        for (int nf = 0; nf < 4; ++nf) {
            bfr[nf][0] = rdB(cur, nf, 0);
            bfr[nf][1] = rdB(cur, nf, 1);
        }
        a0 = rdA(cur, 0, 0); a1 = rdA(cur, 0, 1);
        a2 = rdA(cur, 1, 0); a3 = rdA(cur, 1, 1);
        if (it + 1 < nt) stageA(it + 1, 0);
        __builtin_amdgcn_s_barrier();
        asm volatile("s_waitcnt lgkmcnt(0)" ::: "memory");
        __builtin_amdgcn_sched_barrier(0);
        __builtin_amdgcn_s_setprio(1);
#pragma unroll
        for (int nf = 0; nf < 4; ++nf) {
            MFMA_(acc[0][nf], a0, bfr[nf][0]);
            MFMA_(acc[0][nf], a1, bfr[nf][1]);
            MFMA_(acc[1][nf], a2, bfr[nf][0]);
            MFMA_(acc[1][nf], a3, bfr[nf][1]);
        }
        __builtin_amdgcn_s_setprio(0);
        __builtin_amdgcn_s_barrier();

        // phase 1: A(m2,m3); stage A-half1 of t+1
        a0 = rdA(cur, 2, 0); a1 = rdA(cur, 2, 1);
        a2 = rdA(cur, 3, 0); a3 = rdA(cur, 3, 1);
        if (it + 1 < nt) stageA(it + 1, 1);
        __builtin_amdgcn_s_barrier();
        asm volatile("s_waitcnt lgkmcnt(0)" ::: "memory");
        __builtin_amdgcn_sched_barrier(0);
        __builtin_amdgcn_s_setprio(1);
#pragma unroll
        for (int nf = 0; nf < 4; ++nf) {
            MFMA_(acc[2][nf], a0, bfr[nf][0]);
            MFMA_(acc[2][nf], a1, bfr[nf][1]);
            MFMA_(acc[3][nf], a2, bfr[nf][0]);
            MFMA_(acc[3][nf], a3, bfr[nf][1]);
        }
        __builtin_amdgcn_s_setprio(0);
        __builtin_amdgcn_s_barrier();

        // phase 2: A(m4,m5); stage B-half0 of t+2 (cur B region dead after ph0)
        a0 = rdA(cur, 4, 0); a1 = rdA(cur, 4, 1);
        a2 = rdA(cur, 5, 0); a3 = rdA(cur, 5, 1);
        if (it + 2 < nt) stageB(it + 2, 0);
        __builtin_amdgcn_s_barrier();
        asm volatile("s_waitcnt lgkmcnt(0)" ::: "memory");
        __builtin_amdgcn_sched_barrier(0);
        __builtin_amdgcn_s_setprio(1);
#pragma unroll
        for (int nf = 0; nf < 4; ++nf) {
            MFMA_(acc[4][nf], a0, bfr[nf][0]);
            MFMA_(acc[4][nf], a1, bfr[nf][1]);
            MFMA_(acc[5][nf], a2, bfr[nf][0]);
            MFMA_(acc[5][nf], a3, bfr[nf][1]);
        }
        __builtin_amdgcn_s_setprio(0);
        __builtin_amdgcn_s_barrier();

        // phase 3: A(m6,m7); stage B-half1 of t+2; end-of-tile counted wait
        a0 = rdA(cur, 6, 0); a1 = rdA(cur, 6, 1);
        a2 = rdA(cur, 7, 0); a3 = rdA(cur, 7, 1);
        if (it + 2 < nt) stageB(it + 2, 1);
        __builtin_amdgcn_s_barrier();
        asm volatile("s_waitcnt lgkmcnt(0)" ::: "memory");
        __builtin_amdgcn_sched_barrier(0);
        __builtin_amdgcn_s_setprio(1);
#pragma unroll
        for (int nf = 0; nf < 4; ++nf) {
            MFMA_(acc[6][nf], a0, bfr[nf][0]);
            MFMA_(acc[6][nf], a1, bfr[nf][1]);
            MFMA_(acc[7][nf], a2, bfr[nf][0]);
            MFMA_(acc[7][nf], a3, bfr[nf][1]);
        }
        __builtin_amdgcn_s_setprio(0);
        if (it < nt - 2)       asm volatile("s_waitcnt vmcnt(4)" ::: "memory");
        else if (it == nt - 2) asm volatile("s_waitcnt vmcnt(0)" ::: "memory");
        __builtin_amdgcn_s_barrier();
    }

    // ---------------- epilogue: row-major C [M][N] ----------------
    const int R0 = m0 + wm * 128;
    const int C0 = n0 + wn * 64;
    float bv[4];
#pragma unroll
    for (int j = 0; j < 4; ++j)
        bv[j] = bias ? bias[C0 + j * 16 + fr] : 0.f;

    if (OUT_F32) {
        // fp32 scalar stores: 16 lanes x 4B = full 64B lines, fine directly.
        float* Cb = (float*)Cout + (size_t)bat * sC;
#pragma unroll
        for (int j = 0; j < 4; ++j)
#pragma unroll
            for (int i = 0; i < 8; ++i)
#pragma unroll
                for (int e = 0; e < 4; ++e) {
                    float v = acc[i][j][e] + bv[j];
                    if (RELU) v = fmaxf(v, 0.f);
                    Cb[(size_t)(R0 + i * 16 + r4 + e) * N + C0 + j * 16 + fr] = v;
                }
    } else {
        // LDS bounce: per-wave 16KB slice (K-loop LDS is dead past final barrier).
        // write swizzle: col ^ ((row&7)<<3)  -> read back us8, store 16B/lane.
        unsigned short* sl = Lraw + wv * 8192;
#pragma unroll
        for (int i = 0; i < 8; ++i)
#pragma unroll
            for (int j = 0; j < 4; ++j)
#pragma unroll
                for (int e = 0; e < 4; ++e) {
                    float v = acc[i][j][e] + bv[j];
                    if (RELU) v = fmaxf(v, 0.f);
                    const int row = i * 16 + r4 + e;
                    const int col = j * 16 + fr;
                    sl[row * 64 + (col ^ ((row & 7) << 3))] = f2bf(v);
                }
        unsigned short* Cb = (unsigned short*)Cout + (size_t)bat * sC;
#pragma unroll
        for (int rr = 0; rr < 16; ++rr) {
            const int row = rr * 8 + (lane >> 3);
            const int k8  = lane & 7;
            us8 v = *(const us8*)&sl[row * 64 + ((k8 ^ (row & 7)) << 3)];
            *(us8*)&Cb[(size_t)(R0 + row) * N + C0 + k8 * 8] = v;
        }
    }
}

extern "C" void kernel_launch(void* const* d_in, const int* in_sizes, int n_in,
                              void* d_out, int out_size, void* d_ws, size_t ws_size,
                              hipStream_t stream) {
    constexpr int B = 32, N = 1024, F = 512;

    const float* x0f  = (const float*)d_in[0];
    const float* adjf = (const float*)d_in[1];
    const float* W1 = (const float*)d_in[2];
    const float* b1 = (const float*)d_in[3];
    const float* W2 = (const float*)d_in[4];
    const float* b2 = (const float*)d_in[5];
    const float* W3 = (const float*)d_in[6];
    const float* b3 = (const float*)d_in[7];

    unsigned short* ws   = (unsigned short*)d_ws;
    unsigned short* adjb = ws;                           // B*N*N
    unsigned short* P0   = adjb + (size_t)B * N * N;     // B*N*F  (X buffers)
    unsigned short* P1   = P0 + (size_t)B * N * F;
    unsigned short* PT   = P1 + (size_t)B * N * F;       // B*F*N  (T buffer)
    unsigned short* WT1  = PT + (size_t)B * N * F;
    unsigned short* WT2  = WT1 + (size_t)F * F;
    unsigned short* WT3  = WT2 + (size_t)F * F;

    cvt_f32_bf16<<<2048, 256, 0, stream>>>(adjf, adjb, (long)B * N * N / 4);
    cvt_f32_bf16<<<2048, 256, 0, stream>>>(x0f, P0, (long)B * N * F / 4);
    transpose_cvt<<<(F * F) / 256, 256, 0, stream>>>(W1, WT1, F, F);
    transpose_cvt<<<(F * F) / 256, 256, 0, stream>>>(W2, WT2, F, F);
    transpose_cvt<<<(F * F) / 256, 256, 0, stream>>>(W3, WT3, F, F);

    const int grid = 256;                 // both GEMM shapes: 32 bat x 8 tiles
    const long sX = (long)N * F;          // X / T strides per batch
    const long sAd = (long)N * N;

    // layer 1:  T = WT1 @ X^T ; X1 = relu(adj @ T^T + b1)
    gemm256<false, false><<<grid, 512, 0, stream>>>(WT1,  P0, PT, nullptr, F, N, F, 0,  sX, sX);
    gemm256<true,  false><<<grid, 512, 0, stream>>>(adjb, PT, P1, b1,      N, F, N, sAd, sX, sX);
    // layer 2
    gemm256<false, false><<<grid, 512, 0, stream>>>(WT2,  P1, PT, nullptr, F, N, F, 0,  sX, sX);
    gemm256<true,  false><<<grid, 512, 0, stream>>>(adjb, PT, P0, b2,      N, F, N, sAd, sX, sX);
    // layer 3 (fp32 out, no relu)
    gemm256<false, false><<<grid, 512, 0, stream>>>(WT3,  P0, PT, nullptr, F, N, F, 0,  sX, sX);
    gemm256<false, true ><<<grid, 512, 0, stream>>>(adjb, PT, (float*)d_out, b3, N, F, N, sAd, sX, sX);
}

// Round 4
// 256.251 us; speedup vs baseline: 1.4379x; 1.0534x over previous
//
#include <hip/hip_runtime.h>
#include <hip/hip_bf16.h>

// GCN: 3 x [ relu(A @ (X @ W) + b) ]  (no relu layer 3), fp32 I/O, bf16 MFMA.
// All-row-major chain:
//   G1: T  = W^T @ X^T : gemm(A=WT [F][F], BT=X [N][F]) -> T [F][N]
//   G2: X' = adj @ T^T : gemm(A=adj [N][N], BT=T [F][N]) -> X' [N][F] (+b, relu)
// 256x256 tile, BK=64, 512 thr (8 waves 2Mx4N), dbuf LDS.
// K-loop: read-ahead pipeline — each phase issues NEXT phase's ds_reads and
// MFMAs on regs loaded last phase (k-slice-major phases, 16 MFMA each).
// Stages issue early (ph0/ph1), single vmcnt(0) at ph3 => latency hidden with
// strict cross-wave WAR safety. XOR-swizzled LDS (T2), setprio (T5), XCD
// swizzle (T1), LDS-bounced us8 coalesced epilogue.

typedef __attribute__((ext_vector_type(8))) short bf16x8s;
typedef __attribute__((ext_vector_type(4))) float f32x4;
typedef __attribute__((ext_vector_type(4))) unsigned short us4;
typedef __attribute__((ext_vector_type(8))) unsigned short us8;

__device__ __forceinline__ unsigned short f2bf(float f) {
    unsigned u = __builtin_bit_cast(unsigned, f);
    u += 0x7fffu + ((u >> 16) & 1u);          // RNE
    return (unsigned short)(u >> 16);
}

__device__ __forceinline__ void async16(const unsigned short* g, unsigned short* l) {
    __builtin_amdgcn_global_load_lds(
        (const __attribute__((address_space(1))) unsigned int*)g,
        (__attribute__((address_space(3))) unsigned int*)l, 16, 0, 0);
}

#define MFMA_(d, va, vb) d = __builtin_amdgcn_mfma_f32_16x16x32_bf16(va, vb, d, 0, 0, 0)

// ---------------- prep: x0 f32->bf16 + three W transposes ----------------
__global__ void prep(const float* __restrict__ x0, unsigned short* __restrict__ P0, long n4,
                     const float* __restrict__ W1, const float* __restrict__ W2,
                     const float* __restrict__ W3, unsigned short* __restrict__ WT1,
                     unsigned short* __restrict__ WT2, unsigned short* __restrict__ WT3,
                     int F) {
    long i = (long)blockIdx.x * blockDim.x + threadIdx.x;
    long stride = (long)gridDim.x * blockDim.x;
    for (long k = i; k < n4; k += stride) {
        float4 v = ((const float4*)x0)[k];
        us4 o;
        o.x = f2bf(v.x); o.y = f2bf(v.y); o.z = f2bf(v.z); o.w = f2bf(v.w);
        ((us4*)P0)[k] = o;
    }
    const long FF = (long)F * F;
    for (long k = i; k < 3 * FF; k += stride) {
        int w = (int)(k / FF);
        long idx = k % FF;              // output-linear: coalesced writes
        int r = (int)(idx % F);
        int c = (int)(idx / F);
        const float* W = (w == 0) ? W1 : (w == 1) ? W2 : W3;
        unsigned short* WT = (w == 0) ? WT1 : (w == 1) ? WT2 : WT3;
        WT[idx] = f2bf(W[(size_t)r * F + c]);
    }
}

// ---------------- fp32 -> bf16 convert (x4 vectorized) ----------------
__global__ void cvt_f32_bf16(const float* __restrict__ in, unsigned short* __restrict__ out, long n4) {
    long i = (long)blockIdx.x * blockDim.x + threadIdx.x;
    long stride = (long)gridDim.x * blockDim.x;
    for (; i < n4; i += stride) {
        float4 v = ((const float4*)in)[i];
        us4 o;
        o.x = f2bf(v.x); o.y = f2bf(v.y); o.z = f2bf(v.z); o.w = f2bf(v.w);
        ((us4*)out)[i] = o;
    }
}

// ---------------- batched GEMM C = A @ B,  B given transposed ----------------
template<bool RELU, bool OUT_F32>
__global__ __launch_bounds__(512, 2)
void gemm256(const unsigned short* __restrict__ A,
             const unsigned short* __restrict__ BT,
             void* __restrict__ Cout,
             const float* __restrict__ bias,
             int M, int N, int K,
             long sA, long sBT, long sC)
{
    __shared__ unsigned short Lraw[65536];     // 128 KiB: A dbuf [0,32K) | B dbuf [32K,64K)

    const int t    = threadIdx.x;
    const int lane = t & 63;
    const int wv   = t >> 6;
    const int wm   = wv >> 2;          // 0..1  -> 128-row half
    const int wn   = wv & 3;           // 0..3  -> 64-col strip
    const int fr   = lane & 15;
    const int fk   = (lane >> 4) * 8;
    const int r4   = (lane >> 4) * 4;

    const int tilesN = N >> 8;
    const int bpb    = (M >> 8) * tilesN;
    const int cpx = gridDim.x >> 3;    // grid divisible by 8 -> bijective
    const int lb  = (blockIdx.x & 7) * cpx + (blockIdx.x >> 3);
    const int bat = lb / bpb;
    const int tt  = lb % bpb;
    const int m0  = (tt / tilesN) << 8;
    const int n0  = (tt % tilesN) << 8;

    const unsigned short* Ab = A  + (size_t)bat * sA  + (size_t)m0 * K;
    const unsigned short* Bb = BT + (size_t)bat * sBT + (size_t)n0 * K;

    // staging: chunk c = r*512+t -> LDS elems [c*8, c*8+8) of a 128-row half-tile
    int srow[2], scol[2], lo[2];
#pragma unroll
    for (int r = 0; r < 2; ++r) {
        int c   = r * 512 + t;
        srow[r] = c >> 3;
        scol[r] = ((c & 7) * 8) ^ ((srow[r] & 7) << 3);
        lo[r]   = c * 8;
    }

    auto stageA = [&](int kt, int h) {
        unsigned short* base = Lraw + (kt & 1) * 16384;
#pragma unroll
        for (int r = 0; r < 2; ++r)
            async16(Ab + (size_t)(h * 128 + srow[r]) * K + kt * 64 + scol[r],
                    base + h * 8192 + lo[r]);
    };
    auto stageB = [&](int kt, int h) {
        unsigned short* base = Lraw + 32768 + (kt & 1) * 16384;
#pragma unroll
        for (int r = 0; r < 2; ++r)
            async16(Bb + (size_t)(h * 128 + srow[r]) * K + kt * 64 + scol[r],
                    base + h * 8192 + lo[r]);
    };
    auto rdA = [&](int buf, int mf, int kkj) -> bf16x8s {
        int row = wm * 128 + mf * 16 + fr;
        int e   = (kkj * 32 + fk) ^ ((row & 7) << 3);
        return *(const bf16x8s*)&Lraw[buf * 16384 + row * 64 + e];
    };
    auto rdB = [&](int buf, int nf, int kkj) -> bf16x8s {
        int row = wn * 64 + nf * 16 + fr;
        int e   = (kkj * 32 + fk) ^ ((row & 7) << 3);
        return *(const bf16x8s*)&Lraw[32768 + buf * 16384 + row * 64 + e];
    };

    const int nt = K >> 6;

    f32x4 acc[8][4];
#pragma unroll
    for (int i = 0; i < 8; ++i)
#pragma unroll
        for (int j = 0; j < 4; ++j) acc[i][j] = f32x4{0.f, 0.f, 0.f, 0.f};

    bf16x8s aP[4], aB[4], aC[4], bX[4], bY[4];

    // ---- prologue: stage tile0; read (m0-3,k0) + B(k0) ----
    stageA(0, 0); stageB(0, 0); stageA(0, 1); stageB(0, 1);
    asm volatile("s_waitcnt vmcnt(0)" ::: "memory");
    __builtin_amdgcn_s_barrier();
#pragma unroll
    for (int m = 0; m < 4; ++m) aP[m] = rdA(0, m, 0);
#pragma unroll
    for (int n = 0; n < 4; ++n) bX[n] = rdB(0, n, 0);

    for (int it = 0; it < nt; ++it) {
        const int cur  = it & 1;
        const int nxt  = cur ^ 1;
        const bool more = (it + 1 < nt);

        // ---- ph0: MFMA m0-3 x k0 (aP,bX); read A(m4-7,k0); stage h0 of t+1 ----
        __builtin_amdgcn_s_barrier();
#pragma unroll
        for (int m = 0; m < 4; ++m) aB[m] = rdA(cur, m + 4, 0);
        if (more) { stageA(it + 1, 0); stageB(it + 1, 0); }
        __builtin_amdgcn_s_setprio(1);
#pragma unroll
        for (int m = 0; m < 4; ++m)
#pragma unroll
            for (int n = 0; n < 4; ++n) MFMA_(acc[m][n], aP[m], bX[n]);
        __builtin_amdgcn_s_setprio(0);

        // ---- ph1: MFMA m4-7 x k0 (aB,bX); read A(m0-3,k1)+B(k1); stage h1 ----
        __builtin_amdgcn_s_barrier();
#pragma unroll
        for (int m = 0; m < 4; ++m) aC[m] = rdA(cur, m, 1);
#pragma unroll
        for (int n = 0; n < 4; ++n) bY[n] = rdB(cur, n, 1);
        if (more) { stageA(it + 1, 1); stageB(it + 1, 1); }
        __builtin_amdgcn_s_setprio(1);
#pragma unroll
        for (int m = 0; m < 4; ++m)
#pragma unroll
            for (int n = 0; n < 4; ++n) MFMA_(acc[m + 4][n], aB[m], bX[n]);
        __builtin_amdgcn_s_setprio(0);

        // ---- ph2: MFMA m0-3 x k1 (aC,bY); read A(m4-7,k1) ----
        __builtin_amdgcn_s_barrier();
#pragma unroll
        for (int m = 0; m < 4; ++m) aB[m] = rdA(cur, m + 4, 1);
        __builtin_amdgcn_s_setprio(1);
#pragma unroll
        for (int m = 0; m < 4; ++m)
#pragma unroll
            for (int n = 0; n < 4; ++n) MFMA_(acc[m][n], aC[m], bY[n]);
        __builtin_amdgcn_s_setprio(0);

        // ---- ph3: next-tile visibility; read next (m0-3,k0)+B(k0);
        //          MFMA m4-7 x k1 (aB,bY) ----
        if (more) {
            asm volatile("s_waitcnt vmcnt(0)" ::: "memory");
            __builtin_amdgcn_s_barrier();
#pragma unroll
            for (int m = 0; m < 4; ++m) aP[m] = rdA(nxt, m, 0);
#pragma unroll
            for (int n = 0; n < 4; ++n) bX[n] = rdB(nxt, n, 0);
        }
        __builtin_amdgcn_s_setprio(1);
#pragma unroll
        for (int m = 0; m < 4; ++m)
#pragma unroll
            for (int n = 0; n < 4; ++n) MFMA_(acc[m + 4][n], aB[m], bY[n]);
        __builtin_amdgcn_s_setprio(0);
    }

    __syncthreads();   // all K-loop LDS reads done before epilogue reuses LDS

    // ---------------- epilogue: row-major C [M][N] ----------------
    const int R0 = m0 + wm * 128;
    const int C0 = n0 + wn * 64;
    float bv[4];
#pragma unroll
    for (int j = 0; j < 4; ++j)
        bv[j] = bias ? bias[C0 + j * 16 + fr] : 0.f;

    if (OUT_F32) {
        float* Cb = (float*)Cout + (size_t)bat * sC;
#pragma unroll
        for (int j = 0; j < 4; ++j)
#pragma unroll
            for (int i = 0; i < 8; ++i)
#pragma unroll
                for (int e = 0; e < 4; ++e) {
                    float v = acc[i][j][e] + bv[j];
                    if (RELU) v = fmaxf(v, 0.f);
                    Cb[(size_t)(R0 + i * 16 + r4 + e) * N + C0 + j * 16 + fr] = v;
                }
    } else {
        // LDS bounce -> us8 coalesced stores
        unsigned short* sl = Lraw + wv * 8192;
#pragma unroll
        for (int i = 0; i < 8; ++i)
#pragma unroll
            for (int j = 0; j < 4; ++j)
#pragma unroll
                for (int e = 0; e < 4; ++e) {
                    float v = acc[i][j][e] + bv[j];
                    if (RELU) v = fmaxf(v, 0.f);
                    const int row = i * 16 + r4 + e;
                    const int col = j * 16 + fr;
                    sl[row * 64 + (col ^ ((row & 7) << 3))] = f2bf(v);
                }
        unsigned short* Cb = (unsigned short*)Cout + (size_t)bat * sC;
#pragma unroll
        for (int rr = 0; rr < 16; ++rr) {
            const int row = rr * 8 + (lane >> 3);
            const int k8  = lane & 7;
            us8 v = *(const us8*)&sl[row * 64 + ((k8 ^ (row & 7)) << 3)];
            *(us8*)&Cb[(size_t)(R0 + row) * N + C0 + k8 * 8] = v;
        }
    }
}

extern "C" void kernel_launch(void* const* d_in, const int* in_sizes, int n_in,
                              void* d_out, int out_size, void* d_ws, size_t ws_size,
                              hipStream_t stream) {
    constexpr int B = 32, N = 1024, F = 512;

    const float* x0f  = (const float*)d_in[0];
    const float* adjf = (const float*)d_in[1];
    const float* W1 = (const float*)d_in[2];
    const float* b1 = (const float*)d_in[3];
    const float* W2 = (const float*)d_in[4];
    const float* b2 = (const float*)d_in[5];
    const float* W3 = (const float*)d_in[6];
    const float* b3 = (const float*)d_in[7];

    unsigned short* ws   = (unsigned short*)d_ws;
    unsigned short* adjb = ws;                           // B*N*N
    unsigned short* P0   = adjb + (size_t)B * N * N;     // B*N*F  (X buffers)
    unsigned short* P1   = P0 + (size_t)B * N * F;
    unsigned short* PT   = P1 + (size_t)B * N * F;       // B*F*N  (T buffer)
    unsigned short* WT1  = PT + (size_t)B * N * F;
    unsigned short* WT2  = WT1 + (size_t)F * F;
    unsigned short* WT3  = WT2 + (size_t)F * F;

    prep<<<2048, 256, 0, stream>>>(x0f, P0, (long)B * N * F / 4,
                                   W1, W2, W3, WT1, WT2, WT3, F);
    cvt_f32_bf16<<<2048, 256, 0, stream>>>(adjf, adjb, (long)B * N * N / 4);

    const int grid = 256;                 // both GEMM shapes: 32 bat x 8 tiles
    const long sX = (long)N * F;
    const long sAd = (long)N * N;

    // layer 1
    gemm256<false, false><<<grid, 512, 0, stream>>>(WT1,  P0, PT, nullptr, F, N, F, 0,  sX, sX);
    gemm256<true,  false><<<grid, 512, 0, stream>>>(adjb, PT, P1, b1,      N, F, N, sAd, sX, sX);
    // layer 2
    gemm256<false, false><<<grid, 512, 0, stream>>>(WT2,  P1, PT, nullptr, F, N, F, 0,  sX, sX);
    gemm256<true,  false><<<grid, 512, 0, stream>>>(adjb, PT, P0, b2,      N, F, N, sAd, sX, sX);
    // layer 3 (fp32 out, no relu)
    gemm256<false, false><<<grid, 512, 0, stream>>>(WT3,  P0, PT, nullptr, F, N, F, 0,  sX, sX);
    gemm256<false, true ><<<grid, 512, 0, stream>>>(adjb, PT, (float*)d_out, b3, N, F, N, sAd, sX, sX);
}